// Round 3
// baseline (1291.533 us; speedup 1.0000x reference)
//
#include <hip/hip_runtime.h>

#define T_TOK 2048
#define H_DIM 2048
#define F_DIM 7168
#define E_NUM 8
#define MAX_SLOTS 5120   // 4096 used slots + per-expert pad to 128
#define N13 (2 * F_DIM)  // 14336 combined w1/w3 columns

typedef __attribute__((ext_vector_type(8))) _Float16 f16x8;
typedef __attribute__((ext_vector_type(4))) float    f32x4;

// async global->LDS, 16B per lane; LDS dest is wave-uniform base + lane*16
#define GLL(g, l) __builtin_amdgcn_global_load_lds(                          \
    (const __attribute__((address_space(1))) void*)(g),                      \
    (__attribute__((address_space(3))) void*)(l), 16, 0, 0)

// ---------------- conversion kernels ----------------

// build interleaved w13h: per expert, combined col c: blk=c>>6, sub=c&63;
// source = (sub<32 ? w1 : w3) row f = 32*blk + (sub&31).  fp32 -> fp16.
__global__ __launch_bounds__(256) void cvt13_kernel(const float* __restrict__ w1,
                                                    const float* __restrict__ w3,
                                                    _Float16* __restrict__ w13h) {
    int b = blockIdx.x;                 // e*N13 + c
    int e = b / N13;
    int c = b - e * N13;
    int blk = c >> 6, sub = c & 63;
    int f = blk * 32 + (sub & 31);
    const float* src = (sub < 32 ? w1 : w3) + ((size_t)e * F_DIM + f) * H_DIM + threadIdx.x * 8;
    _Float16* dst = w13h + (size_t)b * H_DIM + threadIdx.x * 8;
    float4 a = *(const float4*)src;
    float4 bb = *(const float4*)(src + 4);
    f16x8 h;
    h[0]=(_Float16)a.x;  h[1]=(_Float16)a.y;  h[2]=(_Float16)a.z;  h[3]=(_Float16)a.w;
    h[4]=(_Float16)bb.x; h[5]=(_Float16)bb.y; h[6]=(_Float16)bb.z; h[7]=(_Float16)bb.w;
    *(f16x8*)dst = h;
}

// fp32 -> fp16 bulk convert, 8 elems/thread, coalesced
__global__ __launch_bounds__(256) void cvtw_kernel(const float* __restrict__ src,
                                                   _Float16* __restrict__ dst) {
    size_t i = ((size_t)blockIdx.x * 256 + threadIdx.x) * 8;
    float4 a = *(const float4*)(src + i);
    float4 b = *(const float4*)(src + i + 4);
    f16x8 h;
    h[0]=(_Float16)a.x; h[1]=(_Float16)a.y; h[2]=(_Float16)a.z; h[3]=(_Float16)a.w;
    h[4]=(_Float16)b.x; h[5]=(_Float16)b.y; h[6]=(_Float16)b.z; h[7]=(_Float16)b.w;
    *(f16x8*)(dst + i) = h;
}

// ---------------- router / bucketing ----------------

__global__ __launch_bounds__(256) void router_kernel(
    const float* __restrict__ x, const float* __restrict__ wg,
    float* __restrict__ logits_out, int* __restrict__ tk_e,
    float* __restrict__ tk_w, int* __restrict__ meta) {
    int wave = threadIdx.x >> 6;
    int lane = threadIdx.x & 63;
    int t = blockIdx.x * 4 + wave;
    const float* xr = x + (size_t)t * H_DIM;

    float xv[32];
#pragma unroll
    for (int i = 0; i < 8; i++) {
        float4 v = *(const float4*)(xr + i * 256 + lane * 4);
        xv[i*4+0] = v.x; xv[i*4+1] = v.y; xv[i*4+2] = v.z; xv[i*4+3] = v.w;
    }
    float lg[E_NUM];
#pragma unroll
    for (int e = 0; e < E_NUM; e++) {
        const float* wr = wg + (size_t)e * H_DIM;
        float acc = 0.f;
#pragma unroll
        for (int i = 0; i < 8; i++) {
            float4 v = *(const float4*)(wr + i * 256 + lane * 4);
            acc += xv[i*4+0]*v.x + xv[i*4+1]*v.y + xv[i*4+2]*v.z + xv[i*4+3]*v.w;
        }
#pragma unroll
        for (int s = 32; s > 0; s >>= 1) acc += __shfl_xor(acc, s, 64);
        lg[e] = acc;
    }
    if (lane == 0) {
        float b0 = -3e38f, b1 = -3e38f; int i0 = 0, i1 = 0;
#pragma unroll
        for (int e = 0; e < E_NUM; e++) {
            float le = lg[e];
            if (le > b0)      { b1 = b0; i1 = i0; b0 = le; i0 = e; }
            else if (le > b1) { b1 = le; i1 = e; }
        }
        float w0 = 1.f / (1.f + __expf(b1 - b0));
        float w1v = 1.f - w0;
#pragma unroll
        for (int e = 0; e < E_NUM; e++) logits_out[(size_t)t * E_NUM + e] = lg[e];
        tk_e[t*2+0] = i0; tk_w[t*2+0] = w0;
        tk_e[t*2+1] = i1; tk_w[t*2+1] = w1v;
        atomicAdd(&meta[i0], 1);
        atomicAdd(&meta[i1], 1);
    }
}

// meta layout: [0..7]=cnt, [8..15]=cnt_pad128, [16..23]=base, [24..31]=fill
__global__ void scan_kernel(int* __restrict__ meta, int* __restrict__ slot_tok,
                            float* __restrict__ slot_w) {
    int lane = threadIdx.x;  // 64 threads
    int cnts[E_NUM], pads[E_NUM], bases[E_NUM];
    int run = 0;
#pragma unroll
    for (int e = 0; e < E_NUM; e++) {
        cnts[e] = meta[e];
        pads[e] = (cnts[e] + 127) & ~127;
        bases[e] = run;
        run += pads[e];
    }
    if (lane < E_NUM) { meta[8 + lane] = pads[lane]; meta[16 + lane] = bases[lane]; }
    for (int e = 0; e < E_NUM; e++)
        for (int i = cnts[e] + lane; i < pads[e]; i += 64) {
            slot_tok[bases[e] + i] = 0;
            slot_w[bases[e] + i] = 0.f;
        }
}

__global__ __launch_bounds__(256) void assign_kernel(
    const int* __restrict__ tk_e, const float* __restrict__ tk_w,
    int* __restrict__ meta, int* __restrict__ slot_tok, float* __restrict__ slot_w) {
    int t = blockIdx.x * 256 + threadIdx.x;
    if (t >= T_TOK) return;
#pragma unroll
    for (int k = 0; k < 2; k++) {
        int e = tk_e[t*2+k];
        int pos = atomicAdd(&meta[24 + e], 1);
        int s = meta[16 + e] + pos;
        slot_tok[s] = t;
        slot_w[s] = tk_w[t*2+k];
    }
}

// ---------------- ffn1: 256x256x(K=64) deep-pipelined grouped GEMM ----------------
// single GEMM over interleaved w13h; epilogue pairs a1 (n=0,1) with a3 (n=2,3)
__global__ __launch_bounds__(512, 2) void ffn1_kernel(
    const _Float16* __restrict__ xb, const _Float16* __restrict__ w13h,
    const int* __restrict__ slot_tok, const int* __restrict__ meta,
    _Float16* __restrict__ hbuf) {
    int e = blockIdx.z;
    int cntpad = meta[8 + e];
    int mb = blockIdx.y;
    if (mb * 256 >= cntpad) return;
    int base = meta[16 + e];
    int nb = blockIdx.x;

    __shared__ _Float16 sA[2][256][64];   // 64 KB
    __shared__ _Float16 sB[2][256][64];   // 64 KB

    int tid  = threadIdx.x;
    int lane = tid & 63;
    int wave = tid >> 6;                  // 0..7
    int wm = wave >> 2, wn = wave & 3;    // 2 (M) x 4 (N)
    int w8 = wave * 8;

    // swizzled read offsets (halves): phys_slot = logical_slot ^ (row&7); row&7 == lane&7
    int lr = lane & 15;
    int sw = lane & 7;
    int sg = lane >> 4;                   // 0..3
    int offk0 = lr * 64 + ((sg    ) ^ sw) * 8;
    int offk1 = lr * 64 + ((sg + 4) ^ sw) * 8;

    // staging: issue q covers rows q*64 + w8 + (lane>>3); source col pre-swizzled
    int rsub = lane >> 3;                         // 0..7
    int sl   = (lane & 7) ^ rsub;                 // logical slot for this lane's phys slot
    int slot0 = base + mb * 256;

    const _Float16* aG[4];
    const _Float16* bG[4];
#pragma unroll
    for (int q = 0; q < 4; q++) {
        int r = mb * 256 + q * 64 + w8 + rsub;    // within-expert row
        int tok = (r < cntpad) ? slot_tok[base + r] : 0;
        aG[q] = xb + (size_t)tok * H_DIM + sl * 8;
        bG[q] = w13h + ((size_t)e * N13 + (size_t)nb * 256 + q * 64 + w8 + rsub) * H_DIM + sl * 8;
    }

    f32x4 zero = {0.f, 0.f, 0.f, 0.f};
    f32x4 acc[8][4];
#pragma unroll
    for (int m = 0; m < 8; m++)
#pragma unroll
        for (int n = 0; n < 4; n++) acc[m][n] = zero;

    const int NT = H_DIM / 64;  // 32
    // prologue: stage tiles 0,1
#pragma unroll
    for (int q = 0; q < 4; q++) GLL(aG[q] + 0,  &sA[0][q*64 + w8][0]);
#pragma unroll
    for (int q = 0; q < 4; q++) GLL(bG[q] + 0,  &sB[0][q*64 + w8][0]);
#pragma unroll
    for (int q = 0; q < 4; q++) GLL(aG[q] + 64, &sA[1][q*64 + w8][0]);
#pragma unroll
    for (int q = 0; q < 4; q++) GLL(bG[q] + 64, &sB[1][q*64 + w8][0]);

    for (int t = 0; t < NT; ++t) {
        if (t < NT - 1) asm volatile("s_waitcnt vmcnt(8)" ::: "memory");
        else            asm volatile("s_waitcnt vmcnt(0)" ::: "memory");
        __builtin_amdgcn_sched_barrier(0);
        __builtin_amdgcn_s_barrier();
        __builtin_amdgcn_sched_barrier(0);
        int bd = t & 1;
        const _Float16* Ab = &sA[bd][wm * 128][0];
        const _Float16* Bb = &sB[bd][wn * 64][0];
        f16x8 bf[2][4];
#pragma unroll
        for (int n = 0; n < 4; n++) {
            bf[0][n] = *(const f16x8*)(const void*)(Bb + n * 1024 + offk0);
            bf[1][n] = *(const f16x8*)(const void*)(Bb + n * 1024 + offk1);
        }
        __builtin_amdgcn_s_setprio(1);
#pragma unroll
        for (int m = 0; m < 8; m++) {
            f16x8 a0 = *(const f16x8*)(const void*)(Ab + m * 1024 + offk0);
            f16x8 a1 = *(const f16x8*)(const void*)(Ab + m * 1024 + offk1);
#pragma unroll
            for (int n = 0; n < 4; n++) {
                acc[m][n] = __builtin_amdgcn_mfma_f32_16x16x32_f16(a0, bf[0][n], acc[m][n], 0, 0, 0);
                acc[m][n] = __builtin_amdgcn_mfma_f32_16x16x32_f16(a1, bf[1][n], acc[m][n], 0, 0, 0);
            }
        }
        __builtin_amdgcn_s_setprio(0);
        __builtin_amdgcn_sched_barrier(0);
        __builtin_amdgcn_s_barrier();
        __builtin_amdgcn_sched_barrier(0);
        if (t + 2 < NT) {
            int k2 = (t + 2) * 64;
#pragma unroll
            for (int q = 0; q < 4; q++) GLL(aG[q] + k2, &sA[bd][q*64 + w8][0]);
#pragma unroll
            for (int q = 0; q < 4; q++) GLL(bG[q] + k2, &sB[bd][q*64 + w8][0]);
        }
    }

    // epilogue: hv = silu(a1)*a3; f = nb*128 + wn*32 + n*16 + lr  (n=0,1)
    int row_e0 = mb * 256 + wm * 128;
    int fb = nb * 128 + wn * 32;
#pragma unroll
    for (int m = 0; m < 8; m++) {
#pragma unroll
        for (int j = 0; j < 4; j++) {
            int re = row_e0 + m * 16 + (lane >> 4) * 4 + j;
            if (re < cntpad) {
                size_t srow = (size_t)(base + re) * F_DIM;
#pragma unroll
                for (int n = 0; n < 2; n++) {
                    float a1 = acc[m][n][j], a3 = acc[m][n + 2][j];
                    float hv = a1 * a3 / (1.f + __expf(-a1));
                    hbuf[srow + fb + n * 16 + lr] = (_Float16)hv;
                }
            }
        }
    }
}

// ---------------- ffn2: 128x256x(K=64) deep-pipelined grouped GEMM ----------------
__global__ __launch_bounds__(512, 2) void ffn2_kernel(
    const _Float16* __restrict__ hbuf, const _Float16* __restrict__ w2h,
    const int* __restrict__ slot_tok, const float* __restrict__ slot_w,
    const int* __restrict__ meta, float* __restrict__ out) {
    int e = blockIdx.z;
    int cntpad = meta[8 + e];
    int mb = blockIdx.y;
    if (mb * 128 >= cntpad) return;
    int base = meta[16 + e];
    int nb = blockIdx.x;

    __shared__ _Float16 sA[2][128][64];   // 32 KB
    __shared__ _Float16 sB[2][256][64];   // 64 KB

    int tid  = threadIdx.x;
    int lane = tid & 63;
    int wave = tid >> 6;
    int wm = wave >> 2, wn = wave & 3;    // 2 (M) x 4 (N); per-wave 64x64
    int w8 = wave * 8;

    int lr = lane & 15;
    int sw = lane & 7;
    int sg = lane >> 4;
    int offk0 = lr * 64 + ((sg    ) ^ sw) * 8;
    int offk1 = lr * 64 + ((sg + 4) ^ sw) * 8;

    int rsub = lane >> 3;
    int sl   = (lane & 7) ^ rsub;
    int slot0 = base + mb * 128;

    const _Float16* aG[2];
    const _Float16* bG[4];
#pragma unroll
    for (int q = 0; q < 2; q++)
        aG[q] = hbuf + (size_t)(slot0 + q * 64 + w8 + rsub) * F_DIM + sl * 8;
#pragma unroll
    for (int q = 0; q < 4; q++)
        bG[q] = w2h + ((size_t)e * H_DIM + (size_t)nb * 256 + q * 64 + w8 + rsub) * F_DIM + sl * 8;

    f32x4 zero = {0.f, 0.f, 0.f, 0.f};
    f32x4 acc[4][4];
#pragma unroll
    for (int m = 0; m < 4; m++)
#pragma unroll
        for (int n = 0; n < 4; n++) acc[m][n] = zero;

    const int NT = F_DIM / 64;  // 112
#pragma unroll
    for (int q = 0; q < 2; q++) GLL(aG[q] + 0,  &sA[0][q*64 + w8][0]);
#pragma unroll
    for (int q = 0; q < 4; q++) GLL(bG[q] + 0,  &sB[0][q*64 + w8][0]);
#pragma unroll
    for (int q = 0; q < 2; q++) GLL(aG[q] + 64, &sA[1][q*64 + w8][0]);
#pragma unroll
    for (int q = 0; q < 4; q++) GLL(bG[q] + 64, &sB[1][q*64 + w8][0]);

    for (int t = 0; t < NT; ++t) {
        if (t < NT - 1) asm volatile("s_waitcnt vmcnt(6)" ::: "memory");
        else            asm volatile("s_waitcnt vmcnt(0)" ::: "memory");
        __builtin_amdgcn_sched_barrier(0);
        __builtin_amdgcn_s_barrier();
        __builtin_amdgcn_sched_barrier(0);
        int bd = t & 1;
        const _Float16* Ab = &sA[bd][wm * 64][0];
        const _Float16* Bb = &sB[bd][wn * 64][0];
        f16x8 bf[2][4];
#pragma unroll
        for (int n = 0; n < 4; n++) {
            bf[0][n] = *(const f16x8*)(const void*)(Bb + n * 1024 + offk0);
            bf[1][n] = *(const f16x8*)(const void*)(Bb + n * 1024 + offk1);
        }
        __builtin_amdgcn_s_setprio(1);
#pragma unroll
        for (int m = 0; m < 4; m++) {
            f16x8 a0 = *(const f16x8*)(const void*)(Ab + m * 1024 + offk0);
            f16x8 a1 = *(const f16x8*)(const void*)(Ab + m * 1024 + offk1);
#pragma unroll
            for (int n = 0; n < 4; n++) {
                acc[m][n] = __builtin_amdgcn_mfma_f32_16x16x32_f16(a0, bf[0][n], acc[m][n], 0, 0, 0);
                acc[m][n] = __builtin_amdgcn_mfma_f32_16x16x32_f16(a1, bf[1][n], acc[m][n], 0, 0, 0);
            }
        }
        __builtin_amdgcn_s_setprio(0);
        __builtin_amdgcn_sched_barrier(0);
        __builtin_amdgcn_s_barrier();
        __builtin_amdgcn_sched_barrier(0);
        if (t + 2 < NT) {
            int k2 = (t + 2) * 64;
#pragma unroll
            for (int q = 0; q < 2; q++) GLL(aG[q] + k2, &sA[bd][q*64 + w8][0]);
#pragma unroll
            for (int q = 0; q < 4; q++) GLL(bG[q] + k2, &sB[bd][q*64 + w8][0]);
        }
    }

    int row0 = mb * 128 + wm * 64;
    int col0 = nb * 256 + wn * 64;
#pragma unroll
    for (int m = 0; m < 4; m++) {
        int rb = row0 + m * 16 + (lane >> 4) * 4;
        int toks[4]; float wts[4];
#pragma unroll
        for (int j = 0; j < 4; j++) {
            int s = base + rb + j;
            toks[j] = slot_tok[s];
            wts[j]  = slot_w[s];
        }
#pragma unroll
        for (int n = 0; n < 4; n++) {
            int col = col0 + n * 16 + lr;
            f32x4 v = acc[m][n];
#pragma unroll
            for (int j = 0; j < 4; j++)
                atomicAdd(&out[(size_t)toks[j] * H_DIM + col], v[j] * wts[j]);
        }
    }
}

// ---------------- launcher ----------------
extern "C" void kernel_launch(void* const* d_in, const int* in_sizes, int n_in,
                              void* d_out, int out_size, void* d_ws, size_t ws_size,
                              hipStream_t stream) {
    const float* x  = (const float*)d_in[0];
    const float* wg = (const float*)d_in[1];
    const float* w1 = (const float*)d_in[2];
    const float* w3 = (const float*)d_in[3];
    const float* w2 = (const float*)d_in[4];
    float* out = (float*)d_out;
    float* logits = out + (size_t)T_TOK * H_DIM;

    const size_t WELEM = (size_t)E_NUM * F_DIM * H_DIM;   // 117,440,512

    char* ws = (char*)d_ws;
    _Float16* w13h = (_Float16*)ws;                       // 2*WELEM fp16 = 448 MiB
    _Float16* w2h  = w13h + 2 * WELEM;                    // 224 MiB
    _Float16* hbuf = w2h + WELEM;                         // 70 MiB
    _Float16* xb   = hbuf + (size_t)MAX_SLOTS * F_DIM;    // 8 MiB
    char* p = (char*)(xb + (size_t)T_TOK * H_DIM);
    int*   slot_tok = (int*)p;   p += MAX_SLOTS * 4;
    float* slot_w   = (float*)p; p += MAX_SLOTS * 4;
    int*   tk_e     = (int*)p;   p += T_TOK * 2 * 4;
    float* tk_w     = (float*)p; p += T_TOK * 2 * 4;
    int*   meta     = (int*)p;   // 32 ints

    hipMemsetAsync(d_out, 0, (size_t)out_size * sizeof(float), stream);
    hipMemsetAsync(meta, 0, 32 * sizeof(int), stream);

    cvt13_kernel<<<dim3(E_NUM * N13), 256, 0, stream>>>(w1, w3, w13h);
    cvtw_kernel<<<dim3(WELEM / (256 * 8)), 256, 0, stream>>>(w2, w2h);
    cvtw_kernel<<<dim3((size_t)T_TOK * H_DIM / (256 * 8)), 256, 0, stream>>>(x, xb);

    router_kernel<<<dim3(T_TOK / 4), 256, 0, stream>>>(x, wg, logits, tk_e, tk_w, meta);
    scan_kernel<<<dim3(1), 64, 0, stream>>>(meta, slot_tok, slot_w);
    assign_kernel<<<dim3(T_TOK / 256), 256, 0, stream>>>(tk_e, tk_w, meta, slot_tok, slot_w);

    ffn1_kernel<<<dim3(N13 / 256, 8, E_NUM), 512, 0, stream>>>(xb, w13h, slot_tok, meta, hbuf);
    ffn2_kernel<<<dim3(H_DIM / 256, 16, E_NUM), 512, 0, stream>>>(hbuf, w2h, slot_tok, slot_w, meta, out);
}